// Round 1
// baseline (83.718 us; speedup 1.0000x reference)
//
#include <hip/hip_runtime.h>

// EncoderSDP: masked path-max gather.
// B=16, L=512, P=32, D=256. out[b,l] = concat(max_p inputs[b, lpath[p]], max_p inputs[b, rpath[p]]),
// zeroed for l >= sent_lens[b].

constexpr int BB = 16;
constexpr int LL = 512;
constexpr int PP = 32;
constexpr int D4 = 64;   // D/4 float4s per row

__device__ __forceinline__ float4 f4max(float4 a, float4 b) {
    return make_float4(fmaxf(a.x, b.x), fmaxf(a.y, b.y),
                       fmaxf(a.z, b.z), fmaxf(a.w, b.w));
}

__global__ __launch_bounds__(128) void encoder_sdp_kernel(
    const float4* __restrict__ inputs,      // [B, L, D4] float4
    const int*    __restrict__ left_paths,  // [B, L, P]
    const int*    __restrict__ right_paths, // [B, L, P]
    const int*    __restrict__ left_lens,   // [B, L]
    const int*    __restrict__ right_lens,  // [B, L]
    const int*    __restrict__ sent_lens,   // [B]
    float4*       __restrict__ out)         // [B, L, 2*D4] float4
{
    const int blk  = blockIdx.x;        // 0..B*L-1
    const int b    = blk & (BB - 1);    // XCD = blk%8 = b%8 -> 2 batches per XCD L2
    const int l    = blk >> 4;
    const int t    = threadIdx.x;
    const int side = t >> 6;            // wave 0 = left, wave 1 = right
    const int lane = t & 63;
    const int bl   = b * LL + l;

    float4* outp = out + (size_t)bl * (2 * D4) + side * D4 + lane;

    if (l >= sent_lens[b]) {
        *outp = make_float4(0.f, 0.f, 0.f, 0.f);
        return;
    }

    const int* paths = side ? right_paths : left_paths;
    const int* lens  = side ? right_lens  : left_lens;
    const int  len   = lens[bl];                              // wave-uniform, >= 1
    const int  myidx = paths[(size_t)bl * PP + (lane & (PP - 1))]; // lane p holds paths[p]

    const float4* base = inputs + (size_t)b * LL * D4 + lane;

    const float NEGV = -1e30f;
    float4 a0 = make_float4(NEGV, NEGV, NEGV, NEGV);
    float4 a1 = a0, a2 = a0, a3 = a0;

    int p = 0;
    for (; p + 4 <= len; p += 4) {
        const int i0 = __shfl(myidx, p + 0, 64);
        const int i1 = __shfl(myidx, p + 1, 64);
        const int i2 = __shfl(myidx, p + 2, 64);
        const int i3 = __shfl(myidx, p + 3, 64);
        const float4 v0 = base[(size_t)i0 * D4];
        const float4 v1 = base[(size_t)i1 * D4];
        const float4 v2 = base[(size_t)i2 * D4];
        const float4 v3 = base[(size_t)i3 * D4];
        a0 = f4max(a0, v0);
        a1 = f4max(a1, v1);
        a2 = f4max(a2, v2);
        a3 = f4max(a3, v3);
    }
    for (; p < len; ++p) {
        const int i0 = __shfl(myidx, p, 64);
        a0 = f4max(a0, base[(size_t)i0 * D4]);
    }

    a0 = f4max(f4max(a0, a1), f4max(a2, a3));
    *outp = a0;
}

extern "C" void kernel_launch(void* const* d_in, const int* in_sizes, int n_in,
                              void* d_out, int out_size, void* d_ws, size_t ws_size,
                              hipStream_t stream) {
    const float4* inputs      = (const float4*)d_in[0];
    const int*    left_paths  = (const int*)d_in[1];
    const int*    right_paths = (const int*)d_in[2];
    const int*    left_lens   = (const int*)d_in[3];
    const int*    right_lens  = (const int*)d_in[4];
    const int*    sent_lens   = (const int*)d_in[5];
    float4*       out         = (float4*)d_out;

    encoder_sdp_kernel<<<BB * LL, 128, 0, stream>>>(
        inputs, left_paths, right_paths, left_lens, right_lens, sent_lens, out);
}

// Round 2
// 81.930 us; speedup vs baseline: 1.0218x; 1.0218x over previous
//
#include <hip/hip_runtime.h>

// EncoderSDP: masked path-max gather.
// B=16, L=512, P=32, D=256.
// out[b,l] = concat(max_p inputs[b, lpath[p]], max_p inputs[b, rpath[p]]), zeroed for l >= sent_lens[b].
//
// R1 design: one wave (64 threads) per (b,l,side). side = blockIdx.y, so the
// path pointer, len, and every path index are block-uniform -> compiler emits
// scalar (s_load) index loads and saddr-form global_load_dwordx4 gathers with
// no per-iteration VALU address work and no ds_bpermute.
// Remainder handled by clamping indices to len-1 (max is idempotent).
// Output stores are non-temporal to keep the gather working set in L2.

constexpr int BB = 16;
constexpr int LL = 512;
constexpr int PP = 32;
constexpr int D4 = 64;   // D/4 float4s per row

typedef float v4f __attribute__((ext_vector_type(4)));

__device__ __forceinline__ v4f v4max(v4f a, v4f b) {
    v4f r;
    r.x = fmaxf(a.x, b.x);
    r.y = fmaxf(a.y, b.y);
    r.z = fmaxf(a.z, b.z);
    r.w = fmaxf(a.w, b.w);
    return r;
}

__global__ __launch_bounds__(64) void encoder_sdp_kernel(
    const v4f* __restrict__ inputs,      // [B, L, D4]
    const int* __restrict__ left_paths,  // [B, L, P]
    const int* __restrict__ right_paths, // [B, L, P]
    const int* __restrict__ left_lens,   // [B, L]
    const int* __restrict__ right_lens,  // [B, L]
    const int* __restrict__ sent_lens,   // [B]
    v4f*       __restrict__ out)         // [B, L, 2*D4]
{
    const int blk  = blockIdx.x;        // 0..B*L-1
    const int side = blockIdx.y;        // 0 = left, 1 = right
    const int b    = blk & (BB - 1);    // XCD = blk%8 = b%8 -> 2 batches per XCD L2
    const int l    = blk >> 4;
    const int lane = threadIdx.x;       // 0..63
    const int bl   = b * LL + l;

    v4f* outp = out + (size_t)bl * (2 * D4) + side * D4 + lane;

    if (l >= sent_lens[b]) {
        v4f z = {0.f, 0.f, 0.f, 0.f};
        __builtin_nontemporal_store(z, outp);
        return;
    }

    const int* paths = side ? right_paths : left_paths;   // uniform select
    const int* lens  = side ? right_lens  : left_lens;
    const int  len   = lens[bl];                          // uniform, >= 1
    const int* pbase = paths + (size_t)bl * PP;

    const v4f* base = inputs + (size_t)b * LL * D4 + lane;

    const float NEGV = -1e30f;
    v4f a0 = {NEGV, NEGV, NEGV, NEGV};
    v4f a1 = a0, a2 = a0, a3 = a0;

    const int lm1 = len - 1;
    const int nch = (len + 3) >> 2;     // chunks of 4, last chunk clamps (max is idempotent)
    for (int c = 0; c < nch; ++c) {
        const int p  = c << 2;
        const int i0 = pbase[p];
        const int i1 = pbase[min(p + 1, lm1)];
        const int i2 = pbase[min(p + 2, lm1)];
        const int i3 = pbase[min(p + 3, lm1)];
        const v4f v0 = base[(size_t)i0 * D4];
        const v4f v1 = base[(size_t)i1 * D4];
        const v4f v2 = base[(size_t)i2 * D4];
        const v4f v3 = base[(size_t)i3 * D4];
        a0 = v4max(a0, v0);
        a1 = v4max(a1, v1);
        a2 = v4max(a2, v2);
        a3 = v4max(a3, v3);
    }

    a0 = v4max(v4max(a0, a1), v4max(a2, a3));
    __builtin_nontemporal_store(a0, outp);
}

extern "C" void kernel_launch(void* const* d_in, const int* in_sizes, int n_in,
                              void* d_out, int out_size, void* d_ws, size_t ws_size,
                              hipStream_t stream) {
    const v4f* inputs      = (const v4f*)d_in[0];
    const int* left_paths  = (const int*)d_in[1];
    const int* right_paths = (const int*)d_in[2];
    const int* left_lens   = (const int*)d_in[3];
    const int* right_lens  = (const int*)d_in[4];
    const int* sent_lens   = (const int*)d_in[5];
    v4f*       out         = (v4f*)d_out;

    encoder_sdp_kernel<<<dim3(BB * LL, 2), 64, 0, stream>>>(
        inputs, left_paths, right_paths, left_lens, right_lens, sent_lens, out);
}

// Round 3
// 81.587 us; speedup vs baseline: 1.0261x; 1.0042x over previous
//
#include <hip/hip_runtime.h>

// EncoderSDP: masked path-max gather.
// B=16, L=512, P=32, D=256.
// out[b,l] = concat(max_p inputs[b, lpath[p]], max_p inputs[b, rpath[p]]), zeroed for l >= sent_lens[b].
//
// R2 design: latency-bound regime (caches are poison-swept before every timed
// launch; gathers are cold random misses). So: maximize memory-level
// parallelism and wave concurrency.
//  - 256-thread blocks (4 waves, one l each) -> 32 waves/CU vs 16 with 64-thr blocks.
//  - side = blockIdx.y (block-uniform); per-wave bl forced into SGPRs via
//    readfirstlane so index loads are SMEM and gather addresses are saddr-form.
//  - 8-wide gather chunks with the NEXT chunk's indices prefetched while the
//    current chunk's gathers are in flight -> ~1 memory round trip per chunk,
//    E[ceil(len/8)] = 2.5 chunks per wave (was ~9 serialized trips in R1).
//  - Tail clamped to pbase[len-1] via uniform selects (max is idempotent).

constexpr int BB = 16;
constexpr int LL = 512;
constexpr int PP = 32;
constexpr int D4 = 64;   // D/4 float4s per row
constexpr int CH = 8;    // gather chunk width

typedef float v4f __attribute__((ext_vector_type(4)));

__device__ __forceinline__ v4f v4max(v4f a, v4f b) {
    v4f r;
    r.x = fmaxf(a.x, b.x);
    r.y = fmaxf(a.y, b.y);
    r.z = fmaxf(a.z, b.z);
    r.w = fmaxf(a.w, b.w);
    return r;
}

__global__ __launch_bounds__(256, 6) void encoder_sdp_kernel(
    const v4f* __restrict__ inputs,      // [B, L, D4]
    const int* __restrict__ left_paths,  // [B, L, P]
    const int* __restrict__ right_paths, // [B, L, P]
    const int* __restrict__ left_lens,   // [B, L]
    const int* __restrict__ right_lens,  // [B, L]
    const int* __restrict__ sent_lens,   // [B]
    v4f*       __restrict__ out)         // [B, L, 2*D4]
{
    const int w    = threadIdx.x >> 6;   // wave 0..3 -> l offset
    const int lane = threadIdx.x & 63;
    const int b    = blockIdx.x & (BB - 1);   // XCD = blk%8 = b%8 -> 2 batches/XCD L2
    const int l    = ((blockIdx.x >> 4) << 2) + w;
    const int side = blockIdx.y;              // 0 = left, 1 = right (block-uniform)
    const int bl   = __builtin_amdgcn_readfirstlane(b * LL + l);

    v4f* outp = out + (size_t)bl * (2 * D4) + side * D4 + lane;

    if (l >= sent_lens[b]) {
        v4f z = {0.f, 0.f, 0.f, 0.f};
        __builtin_nontemporal_store(z, outp);
        return;
    }

    const int* paths = side ? right_paths : left_paths;   // uniform select
    const int* lens  = side ? right_lens  : left_lens;
    const int* pbase = paths + (size_t)bl * PP;

    const int len = __builtin_amdgcn_readfirstlane(lens[bl]);  // >= 1
    const int lm1 = len - 1;

    // Chunk-0 indices + the tail-clamp index, all SMEM loads issued up front.
    int cur[CH];
#pragma unroll
    for (int k = 0; k < CH; ++k) cur[k] = pbase[k];
    const int last = pbase[lm1];

    const v4f* base = inputs + (size_t)b * LL * D4 + lane;

    const float NEGV = -1e30f;
    v4f a0 = {NEGV, NEGV, NEGV, NEGV};
    v4f a1 = a0, a2 = a0, a3 = a0;

    const int nch = (len + CH - 1) / CH;   // 1..4 chunks, uniform
    int p = 0;
    for (int c = 0; c < nch; ++c) {
        // Issue all 8 gathers for the current chunk (indices clamped for tail;
        // all-scalar selects keep addresses in SGPRs).
        v4f v[CH];
#pragma unroll
        for (int k = 0; k < CH; ++k) {
            const int j = (p + k <= lm1) ? cur[k] : last;
            v[k] = base[(size_t)j * D4];
        }
        // Prefetch next chunk's indices while gathers are in flight.
        // (&31 wrap keeps the SMEM access in-bounds; wrapped values are never
        //  selected because of the p+k<=lm1 clamp.)
#pragma unroll
        for (int k = 0; k < CH; ++k) {
            cur[k] = pbase[(p + CH + k) & (PP - 1)];
        }
        // Consume.
        a0 = v4max(a0, v4max(v[0], v[4]));
        a1 = v4max(a1, v4max(v[1], v[5]));
        a2 = v4max(a2, v4max(v[2], v[6]));
        a3 = v4max(a3, v4max(v[3], v[7]));
        p += CH;
    }

    a0 = v4max(v4max(a0, a1), v4max(a2, a3));
    __builtin_nontemporal_store(a0, outp);
}

extern "C" void kernel_launch(void* const* d_in, const int* in_sizes, int n_in,
                              void* d_out, int out_size, void* d_ws, size_t ws_size,
                              hipStream_t stream) {
    const v4f* inputs      = (const v4f*)d_in[0];
    const int* left_paths  = (const int*)d_in[1];
    const int* right_paths = (const int*)d_in[2];
    const int* left_lens   = (const int*)d_in[3];
    const int* right_lens  = (const int*)d_in[4];
    const int* sent_lens   = (const int*)d_in[5];
    v4f*       out         = (v4f*)d_out;

    // grid.x: 16 batches x 128 l-quads; grid.y: side
    encoder_sdp_kernel<<<dim3(BB * (LL / 4), 2), 256, 0, stream>>>(
        inputs, left_paths, right_paths, left_lens, right_lens, sent_lens, out);
}